// Round 6
// baseline (168.490 us; speedup 1.0000x reference)
//
#include <hip/hip_runtime.h>
#include <math.h>

#define N_NODES 50000
#define IN_CH 256
#define N_REL 5
#define N_EDGES 800000
#define N_E4 200000        // N_EDGES/4
#define N_GLOB 20000       // LAST_GLOBALS - LAST_SENSES
#define N_SENSE 25000
#define N_OUT 45000
#define N_QUAD 11250       // N_OUT/4
#define Q_GLOB 5000        // N_GLOB/4 — segment boundary is quad-aligned
#define G3 2048            // k_logits grid: 8 blk/CU — BW-saturating

// ---------------- workspace layout (float offsets from base) ----------------
// Zeroed by ONE hipMemsetAsync node (6176 B): xsum + cntf + agg. No reliance
// on the 0xAA poison anywhere (round-4/5 container failures implicated that).
// xsum  : [0, 1280)      5*256 float accumulators
// cntf  : [1280, 1285)   5 float counters (float adds; compared with fmaxf)
// agg   : [1288, 1544)   256 float accumulators (basis+root GEMV partials)
// pm/ps : [2048, 10240)  per-block online-softmax partials (written before read)
#define WS_XSUM 0
#define WS_CNT 1280
#define WS_AGG 1288
#define WS_PM 2048

// online log-sum-exp merge: (m,s) <- (m,s) ⊕ (m2,s2)
__device__ __forceinline__ void omerge(float& m, float& s, float m2, float s2) {
    float M = fmaxf(m, m2);
    if (M == -INFINITY) return;          // both neutral: avoid inf-inf = NaN
    s = s * expf(m - M) + s2 * expf(m2 - M);
    m = M;
}

// ---------- K1: int4 dst-scan; hits accumulate x[src] into xsum[type] ----------
__global__ __launch_bounds__(256) void k_scan(const float* __restrict__ x,
                                              const int* __restrict__ ei,
                                              const int* __restrict__ et,
                                              float* __restrict__ base) {
    float* xsum = base + WS_XSUM;
    float* cntf = base + WS_CNT;
    int e4 = blockIdx.x * 256 + threadIdx.x;
    if (e4 >= N_E4) return;
    int4 d = ((const int4*)(ei + N_EDGES))[e4];
    int e = e4 * 4;
    for (int k = 0; k < 4; ++k) {
        int dk = (k == 0) ? d.x : (k == 1) ? d.y : (k == 2) ? d.z : d.w;
        if (dk == 0) {                       // ~16 hits total; divergence is rare
            int t = et[e + k];
            atomicAdd(&cntf[t], 1.0f);
            const float4* xr = (const float4*)(x + (size_t)ei[e + k] * IN_CH);
            float* xs = xsum + t * IN_CH;
#pragma unroll 1
            for (int i = 0; i < 64; ++i) {   // 256 fire-and-forget atomics
                float4 v = xr[i];
                atomicAdd(&xs[i * 4 + 0], v.x); atomicAdd(&xs[i * 4 + 1], v.y);
                atomicAdd(&xs[i * 4 + 2], v.z); atomicAdd(&xs[i * 4 + 3], v.w);
            }
        }
    }
}

// ---------- K2: agg = sum_b v[b]@basis[b] + x[0]@root  (24 block-units) ----------
// v[b][d] = sum_r comp[r,b] * xsum[r][d] / max(cnt_r,1)  — W never materialized.
__global__ __launch_bounds__(256) void k_agg(const float* __restrict__ x,
                                             const float* __restrict__ comp,
                                             const float* __restrict__ basis,
                                             const float* __restrict__ root,
                                             float* __restrict__ base) {
    __shared__ float vlds[64];
    const float* xsum = base + WS_XSUM;
    const float* cntf = base + WS_CNT;
    float* agg = base + WS_AGG;
    int bid = blockIdx.x, tid = threadIdx.x;
    float acc = 0.f;
    if (bid < 20) {                          // (b, c) basis GEMV, 4-way K-split
        int b = bid >> 2, c = bid & 3;
        if (tid < 64) {
            int dg = c * 64 + tid;
            float v = 0.f;
#pragma unroll
            for (int r = 0; r < N_REL; ++r)
                v += comp[r * N_REL + b] * xsum[r * IN_CH + dg] / fmaxf(cntf[r], 1.f);
            vlds[tid] = v;
        }
        __syncthreads();
        const float* bp = basis + b * (IN_CH * IN_CH) + c * 64 * IN_CH + tid;
#pragma unroll 8
        for (int dd = 0; dd < 64; ++dd) acc += vlds[dd] * bp[dd * IN_CH];
    } else {                                 // root GEMV, 4-way K-split
        int c = bid - 20;
        const float* xp = x + c * 64;        // uniform broadcast reads
        const float* rp = root + c * 64 * IN_CH + tid;
#pragma unroll 8
        for (int dd = 0; dd < 64; ++dd) acc += xp[dd] * rp[dd * IN_CH];
    }
    atomicAdd(&agg[tid], acc);
}

// ---------- K3: per-lane x1 = relu(bias+agg) + logits + block softmax partials ----------
__global__ __launch_bounds__(256) void k_logits(const float* __restrict__ bias,
                                                const float* __restrict__ Wg,
                                                const float* __restrict__ bg,
                                                const float* __restrict__ Ws,
                                                const float* __restrict__ bs,
                                                float* __restrict__ out,
                                                float* __restrict__ base) {
    __shared__ float rbuf[4][4];
    const float* agg = base + WS_AGG;
    float* pm_g = base + WS_PM;
    float* ps_g = pm_g + G3;
    float* pm_s = ps_g + G3;
    float* ps_s = pm_s + G3;

    int tid = threadIdx.x, bid = blockIdx.x;
    const int lane = tid & 63, w = tid >> 6;

    // x1 slice for this lane: elements 4*lane..4*lane+3 (broadcast L2 reads)
    float4 xv;
    {
        float4 bq = ((const float4*)bias)[lane];
        float4 aq = ((const float4*)agg)[lane];
        xv.x = fmaxf(bq.x + aq.x, 0.f); xv.y = fmaxf(bq.y + aq.y, 0.f);
        xv.z = fmaxf(bq.z + aq.z, 0.f); xv.w = fmaxf(bq.w + aq.w, 0.f);
    }

    float mg = -INFINITY, sg = 0.f, ms = -INFINITY, ss = 0.f;

    for (int q = bid * 4 + w; q < N_QUAD; q += G3 * 4) {   // one wave: 4 rows
        const float* mat; const float* bv; int rl;
        if (q < Q_GLOB) { mat = Wg; bv = bg; rl = q * 4; }
        else            { mat = Ws; bv = bs; rl = q * 4 - N_GLOB; }
        const float4* p = (const float4*)(mat + (size_t)rl * IN_CH);
        float4 a0 = p[lane], a1 = p[64 + lane], a2 = p[128 + lane], a3 = p[192 + lane];
        float d0 = a0.x * xv.x + a0.y * xv.y + a0.z * xv.z + a0.w * xv.w;
        float d1 = a1.x * xv.x + a1.y * xv.y + a1.z * xv.z + a1.w * xv.w;
        float d2 = a2.x * xv.x + a2.y * xv.y + a2.z * xv.z + a2.w * xv.w;
        float d3 = a3.x * xv.x + a3.y * xv.y + a3.z * xv.z + a3.w * xv.w;
#pragma unroll
        for (int off = 32; off; off >>= 1) {
            d0 += __shfl_xor(d0, off); d1 += __shfl_xor(d1, off);
            d2 += __shfl_xor(d2, off); d3 += __shfl_xor(d3, off);
        }
        float4 bq = *(const float4*)(bv + rl);
        float l0 = d0 + bq.x, l1 = d1 + bq.y, l2 = d2 + bq.z, l3 = d3 + bq.w;
        if (lane == 0) ((float4*)out)[q] = make_float4(l0, l1, l2, l3);
        float lm = fmaxf(fmaxf(l0, l1), fmaxf(l2, l3));
        float le = expf(l0 - lm) + expf(l1 - lm) + expf(l2 - lm) + expf(l3 - lm);
        if (q < Q_GLOB) omerge(mg, sg, lm, le);
        else            omerge(ms, ss, lm, le);
    }
    if (lane == 0) { rbuf[w][0] = mg; rbuf[w][1] = sg; rbuf[w][2] = ms; rbuf[w][3] = ss; }
    __syncthreads();
    if (tid == 0) {
        float M0 = rbuf[0][0], S0 = rbuf[0][1], M1 = rbuf[0][2], S1 = rbuf[0][3];
#pragma unroll
        for (int i = 1; i < 4; ++i) {
            omerge(M0, S0, rbuf[i][0], rbuf[i][1]);
            omerge(M1, S1, rbuf[i][2], rbuf[i][3]);
        }
        pm_g[bid] = M0; ps_g[bid] = S0; pm_s[bid] = M1; ps_s[bid] = S1;
    }
}

// ---------- K4: redundant partial-reduce per block, then out -= logZ[segment] ----------
__global__ __launch_bounds__(256) void k_norm(float* __restrict__ out,
                                              const float* __restrict__ base) {
    __shared__ float rm[256], rs[256];
    const float* pm_g = base + WS_PM;
    const float* ps_g = pm_g + G3;
    const float* pm_s = ps_g + G3;
    const float* ps_s = pm_s + G3;
    int tid = threadIdx.x;
    int i = blockIdx.x * 256 + tid;
    float v = (i < N_OUT) ? out[i] : 0.f;    // issue early, overlaps reduction

    float M = -INFINITY, S = 0.f;
#pragma unroll
    for (int j = 0; j < G3 / 256; ++j) omerge(M, S, pm_g[tid + j * 256], ps_g[tid + j * 256]);
    rm[tid] = M; rs[tid] = S; __syncthreads();
    for (int h = 128; h; h >>= 1) {
        if (tid < h) omerge(rm[tid], rs[tid], rm[tid + h], rs[tid + h]);
        __syncthreads();
    }
    float zg = rm[0] + logf(rs[0]);
    __syncthreads();

    M = -INFINITY; S = 0.f;
#pragma unroll
    for (int j = 0; j < G3 / 256; ++j) omerge(M, S, pm_s[tid + j * 256], ps_s[tid + j * 256]);
    rm[tid] = M; rs[tid] = S; __syncthreads();
    for (int h = 128; h; h >>= 1) {
        if (tid < h) omerge(rm[tid], rs[tid], rm[tid + h], rs[tid + h]);
        __syncthreads();
    }
    float zs = rm[0] + logf(rs[0]);

    if (i < N_OUT) out[i] = v - ((i < N_GLOB) ? zg : zs);
}

extern "C" void kernel_launch(void* const* d_in, const int* in_sizes, int n_in,
                              void* d_out, int out_size, void* d_ws, size_t ws_size,
                              hipStream_t stream) {
    const float* x     = (const float*)d_in[0];
    const int*   ei    = (const int*)  d_in[1];
    const int*   et    = (const int*)  d_in[2];
    const float* comp  = (const float*)d_in[3];
    const float* basis = (const float*)d_in[4];
    const float* root  = (const float*)d_in[5];
    const float* bias  = (const float*)d_in[6];
    const float* Wg    = (const float*)d_in[7];
    const float* bg    = (const float*)d_in[8];
    const float* Wsn   = (const float*)d_in[9];
    const float* bs    = (const float*)d_in[10];
    float* out  = (float*)d_out;
    float* base = (float*)d_ws;

    // zero accumulators: xsum(1280f) + cntf(5f) + pad + agg(256f) = 6176 B
    hipMemsetAsync(base, 0, 6176, stream);

    k_scan  <<<(N_E4 + 255) / 256, 256, 0, stream>>>(x, ei, et, base);
    k_agg   <<<24, 256, 0, stream>>>(x, comp, basis, root, base);
    k_logits<<<G3, 256, 0, stream>>>(bias, Wg, bg, Wsn, bs, out, base);
    k_norm  <<<(N_OUT + 255) / 256, 256, 0, stream>>>(out, base);
}